// Round 3
// baseline (10266.053 us; speedup 1.0000x reference)
//
#include <hip/hip_runtime.h>
#include <hip/hip_cooperative_groups.h>
#include <math.h>

namespace cg = cooperative_groups;

#define SEQ    128
#define BATCH  32
#define NINP   1024
#define NGATE  4096   // 4*NINP
#define DEPTH  10
#define NPOL   22     // 2*(DEPTH+1)
#define NVOCAB 32000
#define DEC_OFF 131072000ll   // SEQ*BATCH*NVOCAB

typedef __attribute__((ext_vector_type(8))) short bf16x8;
typedef __attribute__((ext_vector_type(4))) float f32x4;

__device__ __forceinline__ float sigf(float x){ return 1.0f/(1.0f + expf(-x)); }

__device__ __forceinline__ unsigned short f2bf(float x){
  unsigned int u = __float_as_uint(x);
  unsigned int r = (u + 0x7FFFu + ((u >> 16) & 1u)) >> 16;   // RNE
  return (unsigned short)r;
}

// ---------------- init: c0, memory0, h0->bf16 ----------------
__global__ __launch_bounds__(256) void k_init(const float* __restrict__ h0,
    const float* __restrict__ c0, const float* __restrict__ m0,
    float* __restrict__ c, float* __restrict__ mem, unsigned short* __restrict__ h_bf){
  int i = blockIdx.x*256 + threadIdx.x;
  if (i < BATCH*NINP){ c[i] = c0[i]; h_bf[i] = f2bf(h0[i]); }
  if (i < BATCH*DEPTH*NINP){ mem[i] = m0[i]; }
}

// ---------------- w_hh -> bf16, swizzled to per-wave MFMA fragment layout ----------------
// dest flat id = (((nt*4 + q)*8 + kc)*64 + lane)*8 + e
// src: j = nt*16 + (lane&15), k = q*256 + kc*32 + (lane>>4)*8 + e
__global__ __launch_bounds__(256) void k_wconv(const float* __restrict__ w_hh,
    unsigned short* __restrict__ w_swz){
  int id = blockIdx.x*256 + threadIdx.x;          // 0..524287
  int lane = id & 63, kc = (id>>6)&7, q = (id>>9)&3, nt = id>>11;
  int j = nt*16 + (lane&15);
  int k = q*256 + kc*32 + (lane>>4)*8;
  const float* src = w_hh + (size_t)j*NINP + k;
  bf16x8 d;
  #pragma unroll
  for (int e=0;e<8;e++) d[e] = (short)f2bf(src[e]);
  *(bf16x8*)(w_swz + (size_t)id*8) = d;
}

// ---------------- bf16 MFMA GEMM: C[m,n] = sum_k A[m,k]*B[n,k] + bias ----------------
__global__ __launch_bounds__(256) void k_gemm_bf16(
    const float* __restrict__ A, const int* __restrict__ Aidx,
    const float* __restrict__ B, const float* __restrict__ bias0,
    const float* __restrict__ bias1, float* __restrict__ C,
    int K, int ldc){
  __shared__ __align__(16) unsigned short As[128][40];
  __shared__ __align__(16) unsigned short Bs[128][40];
  const int m1 = blockIdx.y*128, n1 = blockIdx.x*128;
  const int tid = threadIdx.x;
  const int wave = tid >> 6, lane = tid & 63;
  const int wr = (wave >> 1) * 64, wc = (wave & 1) * 64;
  const int fr = lane & 15, fq = lane >> 4;

  f32x4 acc[4][4];
  #pragma unroll
  for (int i=0;i<4;i++)
    #pragma unroll
    for (int j=0;j<4;j++) acc[i][j] = (f32x4){0.f,0.f,0.f,0.f};

  const int sr = tid >> 1, sk = (tid & 1) * 16;
  const float* arow = Aidx ? (A + (size_t)Aidx[m1+sr]*K) : (A + (size_t)(m1+sr)*K);
  const float* brow = B + (size_t)(n1+sr)*K;

  for (int k0 = 0; k0 < K; k0 += 32){
    float4 a0 = *(const float4*)(arow + k0 + sk);
    float4 a1 = *(const float4*)(arow + k0 + sk + 4);
    float4 a2 = *(const float4*)(arow + k0 + sk + 8);
    float4 a3 = *(const float4*)(arow + k0 + sk + 12);
    float4 b0 = *(const float4*)(brow + k0 + sk);
    float4 b1 = *(const float4*)(brow + k0 + sk + 4);
    float4 b2 = *(const float4*)(brow + k0 + sk + 8);
    float4 b3 = *(const float4*)(brow + k0 + sk + 12);
    bf16x8 ap0, ap1, bp0, bp1;
    ap0[0]=f2bf(a0.x); ap0[1]=f2bf(a0.y); ap0[2]=f2bf(a0.z); ap0[3]=f2bf(a0.w);
    ap0[4]=f2bf(a1.x); ap0[5]=f2bf(a1.y); ap0[6]=f2bf(a1.z); ap0[7]=f2bf(a1.w);
    ap1[0]=f2bf(a2.x); ap1[1]=f2bf(a2.y); ap1[2]=f2bf(a2.z); ap1[3]=f2bf(a2.w);
    ap1[4]=f2bf(a3.x); ap1[5]=f2bf(a3.y); ap1[6]=f2bf(a3.z); ap1[7]=f2bf(a3.w);
    bp0[0]=f2bf(b0.x); bp0[1]=f2bf(b0.y); bp0[2]=f2bf(b0.z); bp0[3]=f2bf(b0.w);
    bp0[4]=f2bf(b1.x); bp0[5]=f2bf(b1.y); bp0[6]=f2bf(b1.z); bp0[7]=f2bf(b1.w);
    bp1[0]=f2bf(b2.x); bp1[1]=f2bf(b2.y); bp1[2]=f2bf(b2.z); bp1[3]=f2bf(b2.w);
    bp1[4]=f2bf(b3.x); bp1[5]=f2bf(b3.y); bp1[6]=f2bf(b3.z); bp1[7]=f2bf(b3.w);

    __syncthreads();
    *(bf16x8*)&As[sr][sk]     = ap0;
    *(bf16x8*)&As[sr][sk + 8] = ap1;
    *(bf16x8*)&Bs[sr][sk]     = bp0;
    *(bf16x8*)&Bs[sr][sk + 8] = bp1;
    __syncthreads();

    bf16x8 af[4], bf[4];
    #pragma unroll
    for (int mi=0; mi<4; mi++) af[mi] = *(const bf16x8*)&As[wr + mi*16 + fr][fq*8];
    #pragma unroll
    for (int ni=0; ni<4; ni++) bf[ni] = *(const bf16x8*)&Bs[wc + ni*16 + fr][fq*8];
    #pragma unroll
    for (int mi=0; mi<4; mi++)
      #pragma unroll
      for (int ni=0; ni<4; ni++)
        acc[mi][ni] = __builtin_amdgcn_mfma_f32_16x16x32_bf16(af[mi], bf[ni], acc[mi][ni], 0, 0, 0);
  }

  #pragma unroll
  for (int ni=0; ni<4; ni++){
    const int col = n1 + wc + ni*16 + fr;
    const float bv = (bias0 ? bias0[col] : 0.f) + (bias1 ? bias1[col] : 0.f);
    #pragma unroll
    for (int mi=0; mi<4; mi++){
      const int row0 = m1 + wr + mi*16 + fq*4;
      #pragma unroll
      for (int j=0; j<4; j++)
        C[(size_t)(row0 + j)*ldc + col] = acc[mi][ni][j] + bv;
    }
  }
}

// ---------------- xp[m,p] = emb(m) . pol_w[p] + pol_b[p] ----------------
__global__ __launch_bounds__(256) void k_xp(const float* __restrict__ enc,
    const int* __restrict__ inputs, const float* __restrict__ pol_w,
    const float* __restrict__ pol_b, float* __restrict__ xp){
  const int m = blockIdx.x;
  const float* x = enc + (size_t)inputs[m]*NINP;
  __shared__ float xs[NINP];
  for (int i=threadIdx.x; i<NINP; i+=256) xs[i] = x[i];
  __syncthreads();
  const int wave = threadIdx.x >> 6, lane = threadIdx.x & 63;
  for (int p = wave; p < NPOL; p += 4){
    const float* w = pol_w + (size_t)p*NINP;
    float s = 0.f;
    for (int k=lane; k<NINP; k+=64) s = fmaf(xs[k], w[k], s);
    #pragma unroll
    for (int off=32; off; off>>=1) s += __shfl_down(s, off);
    if (lane==0) xp[(size_t)m*NPOL + p] = s + pol_b[p];
  }
}

// ---------------- persistent cooperative scan: 128 steps, 2 grid syncs each ----------------
__global__ __launch_bounds__(256) void k_scan(
    const float* __restrict__ xg, const unsigned short* __restrict__ w_swz,
    const float* __restrict__ conv_w, const float* __restrict__ conv_b,
    const float* __restrict__ xp, float* __restrict__ gates,
    float* __restrict__ c, float* __restrict__ mem, float* __restrict__ logits,
    float* __restrict__ hs, unsigned short* __restrict__ h_bf){
  cg::grid_group grid = cg::this_grid();
  const int blk = blockIdx.x, tid = threadIdx.x;
  const int q = tid >> 6, lane = tid & 63;
  const int fr = lane & 15, fq = lane >> 4;
  const int j0 = blk * 16;
  const int quad = blk >> 6;            // 0,1,3: sigmoid; 2: tanh

  // register-resident w_hh fragments: (n-tile=blk, K-quarter=q)
  bf16x8 wreg[8];
  {
    const unsigned short* wb = w_swz + ((((size_t)blk*4 + q)*8)*64 + (size_t)lane)*8;
    #pragma unroll
    for (int kc=0;kc<8;kc++) wreg[kc] = *(const bf16x8*)(wb + (size_t)kc*512);
  }

  __shared__ float red[4][2][4][64];
  __shared__ float spol[NPOL];

  const unsigned short* hA = h_bf + fr*NINP + q*256 + fq*8;
  const unsigned short* hB = hA + 16*NINP;

  // policy dot assignment: 176 blocks x 4 waves = 704 = 32 b x 22 p
  const int pid = blk*4 + q;
  int pb=0, pp=0, po=0, ptp=0;
  if (blk < 176){ pb = pid/22; pp = pid - pb*22; po = pp/11; ptp = pp - po*11; }

  for (int t=0; t<SEQ; ++t){
    // ---- phase A: gates = act(xg + h @ w_hh^T); policy logits ----
    f32x4 acc0 = {0.f,0.f,0.f,0.f}, acc1 = {0.f,0.f,0.f,0.f};
    #pragma unroll
    for (int kc=0;kc<8;kc++){
      bf16x8 a0 = *(const bf16x8*)(hA + kc*32);
      bf16x8 a1 = *(const bf16x8*)(hB + kc*32);
      acc0 = __builtin_amdgcn_mfma_f32_16x16x32_bf16(a0, wreg[kc], acc0, 0,0,0);
      acc1 = __builtin_amdgcn_mfma_f32_16x16x32_bf16(a1, wreg[kc], acc1, 0,0,0);
    }
    #pragma unroll
    for (int r=0;r<4;r++){ red[q][0][r][lane] = acc0[r]; red[q][1][r][lane] = acc1[r]; }

    float ps = 0.f;
    if (blk < 176){
      if (ptp < DEPTH){
        const float* mr = mem + ((size_t)pb*DEPTH + ptp)*NINP;
        const float* cw = conv_w + po*2*NINP;
        for (int n=lane; n<NINP; n+=64) ps = fmaf(mr[n], cw[2*n], ps);
      }
      if (ptp+1 < DEPTH){
        const float* mr = mem + ((size_t)pb*DEPTH + ptp + 1)*NINP;
        const float* cw = conv_w + po*2*NINP + 1;
        for (int n=lane; n<NINP; n+=64) ps = fmaf(mr[n], cw[2*n], ps);
      }
      #pragma unroll
      for (int off=32; off; off>>=1) ps += __shfl_down(ps, off);
    }
    __syncthreads();

    #pragma unroll
    for (int half=0; half<2; half++){
      int e = tid + half*256;
      int jj = e & 15, b = e >> 4;
      int mi = b >> 4, rt = b & 15;
      int rl = ((rt>>2)<<4) | jj, rg = rt & 3;
      float v = red[0][mi][rg][rl] + red[1][mi][rg][rl]
              + red[2][mi][rg][rl] + red[3][mi][rg][rl];
      v += xg[((size_t)t*BATCH + b)*NGATE + j0 + jj];
      gates[b*NGATE + j0 + jj] = (quad==2) ? tanhf(v) : sigf(v);
    }
    if (blk < 176 && lane == 0)
      logits[pb*NPOL + pp] = ps + conv_b[po] + xp[((size_t)t*BATCH + pb)*NPOL + pp];

    grid.sync();

    // ---- phase B: softmax + LSTM elementwise + stack memory update ----
    const int pbb = blk >> 3;
    if (tid < NPOL) spol[tid] = logits[pbb*NPOL + tid];
    __syncthreads();
    if (tid == 0){
      float mx = spol[0];
      for (int p=1;p<NPOL;p++) mx = fmaxf(mx, spol[p]);
      float sum = 0.f;
      for (int p=0;p<NPOL;p++){ float ev = expf(spol[p]-mx); spol[p]=ev; sum+=ev; }
      float inv = 1.f/sum;
      for (int p=0;p<NPOL;p++) spol[p] *= inv;
    }
    __syncthreads();
    if (tid < 128){
      const int e = blk*128 + tid, b = e >> 10, n = e & 1023;
      float gi = gates[b*NGATE + n];
      float gf = gates[b*NGATE + NINP + n];
      float gg = gates[b*NGATE + 2*NINP + n];
      float go = gates[b*NGATE + 3*NINP + n];
      float cc = gf*c[e] + gi*gg;
      float hh = go*tanhf(cc);
      c[e] = cc;
      hs[(size_t)t*(BATCH*NINP) + e] = hh;
      h_bf[e] = f2bf(hh);
      float p[NPOL];
      #pragma unroll
      for (int k=0;k<NPOL;k++) p[k] = spol[k];
      float psum = 0.f;
      #pragma unroll
      for (int k=11;k<22;k++) psum += p[k];
      float m[DEPTH];
      #pragma unroll
      for (int j=0;j<DEPTH;j++) m[j] = mem[((size_t)b*DEPTH + j)*NINP + n];
      float outv[DEPTH];
      {
        float v = psum*hh;
        #pragma unroll
        for (int j=0;j<DEPTH;j++) v = fmaf(p[j], m[j], v);
        outv[0] = v;
      }
      #pragma unroll
      for (int d=1; d<DEPTH; d++){
        float v = 0.f;
        for (int j=d;   j<DEPTH; j++) v = fmaf(p[j-d],    m[j], v);
        for (int j=d-1; j<DEPTH; j++) v = fmaf(p[12+j-d], m[j], v);
        outv[d] = v;
      }
      #pragma unroll
      for (int d=0; d<DEPTH; d++) mem[((size_t)b*DEPTH + d)*NINP + n] = outv[d];
    }
    grid.sync();
  }
}

// ---------------- tail: hT, cT, memT ----------------
__global__ __launch_bounds__(256) void k_tail(const float* __restrict__ hs,
    const float* __restrict__ c, const float* __restrict__ mem, float* __restrict__ out){
  int i = blockIdx.x*256 + threadIdx.x;
  float* o = out + DEC_OFF;
  if (i < BATCH*NINP){ o[i] = hs[(size_t)127*BATCH*NINP + i]; o[BATCH*NINP + i] = c[i]; }
  if (i < BATCH*DEPTH*NINP){ o[2*BATCH*NINP + i] = mem[i]; }
}

extern "C" void kernel_launch(void* const* d_in, const int* in_sizes, int n_in,
                              void* d_out, int out_size, void* d_ws, size_t ws_size,
                              hipStream_t stream){
  (void)in_sizes; (void)n_in; (void)out_size; (void)ws_size;
  const int*   inputs = (const int*)  d_in[0];
  const float* h0     = (const float*)d_in[1];
  const float* c0     = (const float*)d_in[2];
  const float* m0     = (const float*)d_in[3];
  const float* enc    = (const float*)d_in[4];
  const float* dbias  = (const float*)d_in[5];
  const float* w_ih   = (const float*)d_in[6];
  const float* w_hh   = (const float*)d_in[7];
  const float* b_ih   = (const float*)d_in[8];
  const float* b_hh   = (const float*)d_in[9];
  const float* conv_w = (const float*)d_in[10];
  const float* conv_b = (const float*)d_in[11];
  const float* pol_w  = (const float*)d_in[12];
  const float* pol_b  = (const float*)d_in[13];

  float* out = (float*)d_out;
  float* ws  = (float*)d_ws;
  // ws layout (floats): hs 4194304 | gates 131072 | c 32768 | mem 327680 | xp 90112 | logits 704
  float* hs     = ws;
  float* gates  = hs    + 4194304;
  float* cbuf   = gates + 131072;
  float* memw   = cbuf  + 32768;
  float* xp     = memw  + 327680;
  float* logits = xp    + 90112;
  // big scratch inside the decoded region of d_out (consumed before decode overwrites):
  float* xg = out;                                              // 16.7M floats
  unsigned short* w_swz = (unsigned short*)(out + 17000000);    // 4.2M shorts
  unsigned short* h_bf  = (unsigned short*)(out + 19500000);    // 32768 shorts

  k_init<<<1280, 256, 0, stream>>>(h0, c0, m0, cbuf, memw, h_bf);
  k_wconv<<<2048, 256, 0, stream>>>(w_hh, w_swz);

  dim3 gxg(32, 32);
  k_gemm_bf16<<<gxg, 256, 0, stream>>>(enc, inputs, w_ih, b_ih, b_hh, xg, NINP, NGATE);
  k_xp<<<SEQ*BATCH, 256, 0, stream>>>(enc, inputs, pol_w, pol_b, xp);

  {
    const float* xg_a = xg; const unsigned short* wz_a = w_swz;
    const float* cw_a = conv_w; const float* cb_a = conv_b;
    const float* xp_a = xp; float* g_a = gates; float* c_a = cbuf;
    float* m_a = memw; float* l_a = logits; float* hs_a = hs;
    unsigned short* hb_a = h_bf;
    void* args[] = {(void*)&xg_a, (void*)&wz_a, (void*)&cw_a, (void*)&cb_a,
                    (void*)&xp_a, (void*)&g_a, (void*)&c_a, (void*)&m_a,
                    (void*)&l_a, (void*)&hs_a, (void*)&hb_a};
    hipLaunchCooperativeKernel((void*)k_scan, dim3(256), dim3(256), args, 0, stream);
  }

  dim3 gdec(250, 32);
  k_gemm_bf16<<<gdec, 256, 0, stream>>>(hs, nullptr, enc, dbias, nullptr, out, NINP, NVOCAB);

  k_tail<<<1280, 256, 0, stream>>>(hs, cbuf, memw, out);
}

// Round 4
// 7158.382 us; speedup vs baseline: 1.4341x; 1.4341x over previous
//
#include <hip/hip_runtime.h>
#include <math.h>

#define SEQ    128
#define BATCH  32
#define NINP   1024
#define NGATE  4096   // 4*NINP
#define DEPTH  10
#define NPOL   22     // 2*(DEPTH+1)
#define NVOCAB 32000
#define DEC_OFF 131072000ll   // SEQ*BATCH*NVOCAB

typedef __attribute__((ext_vector_type(8))) short bf16x8;
typedef __attribute__((ext_vector_type(4))) float f32x4;

__device__ __forceinline__ float sigf(float x){ return 1.0f/(1.0f + expf(-x)); }

__device__ __forceinline__ unsigned short f2bf(float x){
  unsigned int u = __float_as_uint(x);
  unsigned int r = (u + 0x7FFFu + ((u >> 16) & 1u)) >> 16;   // RNE
  return (unsigned short)r;
}

// ---------------- init: c0 (transposed slab layout), memory0 -> [b][n][d], h0 -> bf16 ----------------
__global__ __launch_bounds__(256) void k_init(const float* __restrict__ h0,
    const float* __restrict__ c0, const float* __restrict__ m0,
    float* __restrict__ cbuf, float* __restrict__ memw, unsigned short* __restrict__ h_bf){
  int i = blockIdx.x*256 + threadIdx.x;
  if (i < BATCH*NINP){
    int b = i >> 10, n = i & 1023;
    cbuf[(n>>4)*512 + b*16 + (n&15)] = c0[i];
    h_bf[i] = f2bf(h0[i]);
  }
  if (i < BATCH*DEPTH*NINP){
    int b = i/10240, r = i - b*10240, d = r >> 10, n = r & 1023;
    memw[((size_t)b*NINP + n)*DEPTH + d] = m0[i];
  }
}

// ---------------- w_hh -> bf16, swizzled to per-wave MFMA fragment layout ----------------
// dest flat id = (((nt*4 + kq)*8 + kc)*64 + lane)*8 + e
// src: j = nt*16 + (lane&15), k = kq*256 + kc*32 + (lane>>4)*8 + e
__global__ __launch_bounds__(256) void k_wconv(const float* __restrict__ w_hh,
    unsigned short* __restrict__ w_swz){
  int id = blockIdx.x*256 + threadIdx.x;          // 0..524287
  int lane = id & 63, kc = (id>>6)&7, kq = (id>>9)&3, nt = id>>11;
  int j = nt*16 + (lane&15);
  int k = kq*256 + kc*32 + (lane>>4)*8;
  const float* src = w_hh + (size_t)j*NINP + k;
  bf16x8 d;
  #pragma unroll
  for (int e=0;e<8;e++) d[e] = (short)f2bf(src[e]);
  *(bf16x8*)(w_swz + (size_t)id*8) = d;
}

// ---------------- bf16 MFMA GEMM: C[m,n] = sum_k A[m,k]*B[n,k] + bias ----------------
__global__ __launch_bounds__(256) void k_gemm_bf16(
    const float* __restrict__ A, const int* __restrict__ Aidx,
    const float* __restrict__ B, const float* __restrict__ bias0,
    const float* __restrict__ bias1, float* __restrict__ C,
    int K, int ldc){
  __shared__ __align__(16) unsigned short As[128][40];
  __shared__ __align__(16) unsigned short Bs[128][40];
  const int m1 = blockIdx.y*128, n1 = blockIdx.x*128;
  const int tid = threadIdx.x;
  const int wave = tid >> 6, lane = tid & 63;
  const int wr = (wave >> 1) * 64, wc = (wave & 1) * 64;
  const int fr = lane & 15, fq = lane >> 4;

  f32x4 acc[4][4];
  #pragma unroll
  for (int i=0;i<4;i++)
    #pragma unroll
    for (int j=0;j<4;j++) acc[i][j] = (f32x4){0.f,0.f,0.f,0.f};

  const int sr = tid >> 1, sk = (tid & 1) * 16;
  const float* arow = Aidx ? (A + (size_t)Aidx[m1+sr]*K) : (A + (size_t)(m1+sr)*K);
  const float* brow = B + (size_t)(n1+sr)*K;

  for (int k0 = 0; k0 < K; k0 += 32){
    float4 a0 = *(const float4*)(arow + k0 + sk);
    float4 a1 = *(const float4*)(arow + k0 + sk + 4);
    float4 a2 = *(const float4*)(arow + k0 + sk + 8);
    float4 a3 = *(const float4*)(arow + k0 + sk + 12);
    float4 b0 = *(const float4*)(brow + k0 + sk);
    float4 b1 = *(const float4*)(brow + k0 + sk + 4);
    float4 b2 = *(const float4*)(brow + k0 + sk + 8);
    float4 b3 = *(const float4*)(brow + k0 + sk + 12);
    bf16x8 ap0, ap1, bp0, bp1;
    ap0[0]=f2bf(a0.x); ap0[1]=f2bf(a0.y); ap0[2]=f2bf(a0.z); ap0[3]=f2bf(a0.w);
    ap0[4]=f2bf(a1.x); ap0[5]=f2bf(a1.y); ap0[6]=f2bf(a1.z); ap0[7]=f2bf(a1.w);
    ap1[0]=f2bf(a2.x); ap1[1]=f2bf(a2.y); ap1[2]=f2bf(a2.z); ap1[3]=f2bf(a2.w);
    ap1[4]=f2bf(a3.x); ap1[5]=f2bf(a3.y); ap1[6]=f2bf(a3.z); ap1[7]=f2bf(a3.w);
    bp0[0]=f2bf(b0.x); bp0[1]=f2bf(b0.y); bp0[2]=f2bf(b0.z); bp0[3]=f2bf(b0.w);
    bp0[4]=f2bf(b1.x); bp0[5]=f2bf(b1.y); bp0[6]=f2bf(b1.z); bp0[7]=f2bf(b1.w);
    bp1[0]=f2bf(b2.x); bp1[1]=f2bf(b2.y); bp1[2]=f2bf(b2.z); bp1[3]=f2bf(b2.w);
    bp1[4]=f2bf(b3.x); bp1[5]=f2bf(b3.y); bp1[6]=f2bf(b3.z); bp1[7]=f2bf(b3.w);

    __syncthreads();
    *(bf16x8*)&As[sr][sk]     = ap0;
    *(bf16x8*)&As[sr][sk + 8] = ap1;
    *(bf16x8*)&Bs[sr][sk]     = bp0;
    *(bf16x8*)&Bs[sr][sk + 8] = bp1;
    __syncthreads();

    bf16x8 af[4], bf[4];
    #pragma unroll
    for (int mi=0; mi<4; mi++) af[mi] = *(const bf16x8*)&As[wr + mi*16 + fr][fq*8];
    #pragma unroll
    for (int ni=0; ni<4; ni++) bf[ni] = *(const bf16x8*)&Bs[wc + ni*16 + fr][fq*8];
    #pragma unroll
    for (int mi=0; mi<4; mi++)
      #pragma unroll
      for (int ni=0; ni<4; ni++)
        acc[mi][ni] = __builtin_amdgcn_mfma_f32_16x16x32_bf16(af[mi], bf[ni], acc[mi][ni], 0, 0, 0);
  }

  #pragma unroll
  for (int ni=0; ni<4; ni++){
    const int col = n1 + wc + ni*16 + fr;
    const float bv = (bias0 ? bias0[col] : 0.f) + (bias1 ? bias1[col] : 0.f);
    #pragma unroll
    for (int mi=0; mi<4; mi++){
      const int row0 = m1 + wr + mi*16 + fq*4;
      #pragma unroll
      for (int j=0; j<4; j++)
        C[(size_t)(row0 + j)*ldc + col] = acc[mi][ni][j] + bv;
    }
  }
}

// ---------------- logits[t][b][p] = emb(t,b).pol_w[p] + pol_b[p] + conv_b[p/11] ----------------
__global__ __launch_bounds__(256) void k_xp(const float* __restrict__ enc,
    const int* __restrict__ inputs, const float* __restrict__ pol_w,
    const float* __restrict__ pol_b, const float* __restrict__ conv_b,
    float* __restrict__ logits){
  const int m = blockIdx.x;
  const float* x = enc + (size_t)inputs[m]*NINP;
  __shared__ float xs[NINP];
  for (int i=threadIdx.x; i<NINP; i+=256) xs[i] = x[i];
  __syncthreads();
  const int wave = threadIdx.x >> 6, lane = threadIdx.x & 63;
  for (int p = wave; p < NPOL; p += 4){
    const float* w = pol_w + (size_t)p*NINP;
    float s = 0.f;
    for (int k=lane; k<NINP; k+=64) s = fmaf(xs[k], w[k], s);
    #pragma unroll
    for (int off=32; off; off>>=1) s += __shfl_down(s, off);
    if (lane==0) logits[(size_t)m*NPOL + p] = s + pol_b[p] + conv_b[p/11];
  }
}

// ---------------- seed logits[0] with conv(mem0) (m0 original [b][d][n] layout) ----------------
__global__ __launch_bounds__(256) void k_pol0(const float* __restrict__ m0,
    const float* __restrict__ conv_w, float* __restrict__ logits){
  const int b = blockIdx.x;
  const int wave = threadIdx.x >> 6, lane = threadIdx.x & 63;
  for (int p = wave; p < NPOL; p += 4){
    const int o = p/11, tp = p - o*11;
    float s = 0.f;
    if (tp < DEPTH){
      const float* mr = m0 + ((size_t)b*DEPTH + tp)*NINP;
      for (int n=lane; n<NINP; n+=64) s = fmaf(mr[n], conv_w[o*2*NINP + 2*n], s);
    }
    if (tp+1 < DEPTH){
      const float* mr = m0 + ((size_t)b*DEPTH + tp + 1)*NINP;
      for (int n=lane; n<NINP; n+=64) s = fmaf(mr[n], conv_w[o*2*NINP + 2*n + 1], s);
    }
    #pragma unroll
    for (int off=32; off; off>>=1) s += __shfl_down(s, off);
    if (lane==0) logits[b*NPOL + p] += s;
  }
}

// ---------------- fused step: 64 blocks x 256 threads, no grid sync ----------------
// block blk owns n-slice [blk*16, blk*16+16) across all 4 gate quadrants.
__global__ __launch_bounds__(256) void k_step(
    const float* __restrict__ xg, const unsigned short* __restrict__ w_swz,
    const float* __restrict__ conv_w, float* __restrict__ logits,
    float* __restrict__ cbuf, float* __restrict__ memw,
    float* __restrict__ hs, unsigned short* __restrict__ h_bf, int t){
  const int blk = blockIdx.x, tid = threadIdx.x;
  const int q = tid >> 6, lane = tid & 63;        // wave q = gate quadrant
  const int fr = lane & 15, fq = lane >> 4;
  const int n0 = blk * 16;

  // ---- issue w fragment loads early (L3-resident, stay in VGPRs) ----
  bf16x8 wreg[32];
  const unsigned short* wb = w_swz + ((size_t)(q*64 + blk)*32*64 + lane)*8;
  #pragma unroll
  for (int ks=0; ks<32; ks++) wreg[ks] = *(const bf16x8*)(wb + ks*512);

  // ---- stage h (32x1024 bf16) into XOR-swizzled LDS ----
  __shared__ __align__(16) unsigned short hlds[32*1024];
  {
    const int b = tid >> 3, seg = tid & 7;
    const bf16x8* src = (const bf16x8*)(h_bf + b*NINP + seg*128);
    #pragma unroll
    for (int i=0;i<16;i++){
      int chunk = seg*16 + i;                       // 16B units within row
      ((bf16x8*)hlds)[b*128 + (chunk ^ (b&7))] = src[i];
    }
  }

  // ---- softmax of logits[t] (32 small softmaxes, one thread each) ----
  __shared__ float spol[32][NPOL];
  if (tid < 32){
    const float* lg = logits + (size_t)t*(BATCH*NPOL) + tid*NPOL;
    float l[NPOL]; float mx = -1e30f;
    #pragma unroll
    for (int p=0;p<NPOL;p++){ l[p] = lg[p]; mx = fmaxf(mx, l[p]); }
    float sum = 0.f;
    #pragma unroll
    for (int p=0;p<NPOL;p++){ l[p] = expf(l[p]-mx); sum += l[p]; }
    float inv = 1.f/sum;
    #pragma unroll
    for (int p=0;p<NPOL;p++) spol[tid][p] = l[p]*inv;
  }
  __syncthreads();

  // ---- matmul: gates_raw[b, q*1024 + n0 + fr] over K=1024 ----
  f32x4 acc0 = {0.f,0.f,0.f,0.f}, acc1 = {0.f,0.f,0.f,0.f};
  #pragma unroll
  for (int ks=0; ks<32; ks++){
    bf16x8 a0 = ((const bf16x8*)hlds)[fr*128      + ((ks*4 + fq) ^ (fr&7))];
    bf16x8 a1 = ((const bf16x8*)hlds)[(16+fr)*128 + ((ks*4 + fq) ^ (fr&7))];
    acc0 = __builtin_amdgcn_mfma_f32_16x16x32_bf16(a0, wreg[ks], acc0, 0,0,0);
    acc1 = __builtin_amdgcn_mfma_f32_16x16x32_bf16(a1, wreg[ks], acc1, 0,0,0);
  }

  // ---- exchange gates via LDS: gl[b][q*16 + j] ----
  __shared__ float gl[32][68];
  #pragma unroll
  for (int r=0;r<4;r++){
    gl[fq*4 + r][q*16 + fr]      = acc0[r];
    gl[16 + fq*4 + r][q*16 + fr] = acc1[r];
  }
  __syncthreads();

  // ---- LSTM elementwise + stack memory update + policy partials for t+1 ----
  #pragma unroll
  for (int half=0; half<2; half++){
    const int e = tid + half*256;                 // 0..511
    const int b = e >> 4, j = e & 15, n = n0 + j;
    const float* xr = xg + ((size_t)t*BATCH + b)*NGATE + n;
    float gi = sigf (gl[b][j]      + xr[0]);
    float gf = sigf (gl[b][16+j]   + xr[NINP]);
    float gg = tanhf(gl[b][32+j]   + xr[2*NINP]);
    float go = sigf (gl[b][48+j]   + xr[3*NINP]);
    float cc = gf*cbuf[blk*512 + e] + gi*gg;
    float hh = go*tanhf(cc);
    cbuf[blk*512 + e] = cc;
    hs[((size_t)t*BATCH + b)*NINP + n] = hh;
    h_bf[b*NINP + n] = f2bf(hh);

    float p_[NPOL];
    #pragma unroll
    for (int k2=0;k2<NPOL;k2++) p_[k2] = spol[b][k2];
    float psum = 0.f;
    #pragma unroll
    for (int k2=11;k2<22;k2++) psum += p_[k2];

    float* mw = memw + ((size_t)b*NINP + n)*DEPTH;
    float m[DEPTH];
    #pragma unroll
    for (int d=0;d<DEPTH;d++) m[d] = mw[d];
    float outv[DEPTH];
    {
      float v = psum*hh;
      #pragma unroll
      for (int jj=0;jj<DEPTH;jj++) v = fmaf(p_[jj], m[jj], v);
      outv[0] = v;
    }
    #pragma unroll
    for (int d=1; d<DEPTH; d++){
      float v = 0.f;
      for (int jj=d;   jj<DEPTH; jj++) v = fmaf(p_[jj-d],    m[jj], v);
      for (int jj=d-1; jj<DEPTH; jj++) v = fmaf(p_[12+jj-d], m[jj], v);
      outv[d] = v;
    }
    #pragma unroll
    for (int d=0;d<DEPTH;d++) mw[d] = outv[d];

    // policy partials from updated mem (for logits[t+1])
    float part[NPOL];
    #pragma unroll
    for (int o2=0;o2<2;o2++){
      const float c0t = conv_w[o2*2*NINP + 2*n];
      const float c1t = conv_w[o2*2*NINP + 2*n + 1];
      #pragma unroll
      for (int tp=0;tp<11;tp++){
        float v = 0.f;
        if (tp < DEPTH)   v = outv[tp]*c0t;
        if (tp+1 < DEPTH) v = fmaf(outv[tp+1], c1t, v);
        part[o2*11+tp] = v;
      }
    }
    #pragma unroll
    for (int pp2=0; pp2<NPOL; pp2++){
      float v = part[pp2];
      v += __shfl_xor(v, 1); v += __shfl_xor(v, 2);
      v += __shfl_xor(v, 4); v += __shfl_xor(v, 8);
      if (j == 0) atomicAdd(&logits[(size_t)(t+1)*(BATCH*NPOL) + b*NPOL + pp2], v);
    }
  }
}

// ---------------- tail: hT, cT, memT (undo working layouts) ----------------
__global__ __launch_bounds__(256) void k_tail(const float* __restrict__ hs,
    const float* __restrict__ cbuf, const float* __restrict__ memw,
    float* __restrict__ out){
  int i = blockIdx.x*256 + threadIdx.x;
  float* o = out + DEC_OFF;
  if (i < BATCH*NINP){
    int b = i >> 10, n = i & 1023;
    o[i] = hs[(size_t)127*BATCH*NINP + i];
    o[BATCH*NINP + i] = cbuf[(n>>4)*512 + b*16 + (n&15)];
  }
  if (i < BATCH*DEPTH*NINP){
    int b = i/10240, r = i - b*10240, d = r >> 10, n = r & 1023;
    o[2*BATCH*NINP + i] = memw[((size_t)b*NINP + n)*DEPTH + d];
  }
}

extern "C" void kernel_launch(void* const* d_in, const int* in_sizes, int n_in,
                              void* d_out, int out_size, void* d_ws, size_t ws_size,
                              hipStream_t stream){
  (void)in_sizes; (void)n_in; (void)out_size; (void)ws_size;
  const int*   inputs = (const int*)  d_in[0];
  const float* h0     = (const float*)d_in[1];
  const float* c0     = (const float*)d_in[2];
  const float* m0     = (const float*)d_in[3];
  const float* enc    = (const float*)d_in[4];
  const float* dbias  = (const float*)d_in[5];
  const float* w_ih   = (const float*)d_in[6];
  const float* w_hh   = (const float*)d_in[7];
  const float* b_ih   = (const float*)d_in[8];
  const float* b_hh   = (const float*)d_in[9];
  const float* conv_w = (const float*)d_in[10];
  const float* conv_b = (const float*)d_in[11];
  const float* pol_w  = (const float*)d_in[12];
  const float* pol_b  = (const float*)d_in[13];

  float* out = (float*)d_out;
  float* ws  = (float*)d_ws;
  // ws layout (floats): hs 4194304 | cbuf 32768 | memw 327680 | logits 129*704
  float* hs     = ws;
  float* cbuf   = hs   + 4194304;
  float* memw   = cbuf + 32768;
  float* logits = memw + 327680;
  // big scratch inside the decoded region of d_out (consumed before decode overwrites):
  float* xg = out;                                              // 16.7M floats
  unsigned short* w_swz = (unsigned short*)(out + 17000000);    // 4.2M shorts
  unsigned short* h_bf  = (unsigned short*)(out + 19500000);    // 32768 shorts

  k_init<<<1280, 256, 0, stream>>>(h0, c0, m0, cbuf, memw, h_bf);
  k_wconv<<<2048, 256, 0, stream>>>(w_hh, w_swz);

  // xg[m,j] = emb(m).w_ih[j] + b_ih[j] + b_hh[j]   (4096x4096x1024 bf16 MFMA)
  dim3 gxg(32, 32);
  k_gemm_bf16<<<gxg, 256, 0, stream>>>(enc, inputs, w_ih, b_ih, b_hh, xg, NINP, NGATE);

  // logits[t] = xp(t) + pol_b + conv_b  (all 128 steps), then seed t=0 with conv(mem0)
  k_xp<<<SEQ*BATCH, 256, 0, stream>>>(enc, inputs, pol_w, pol_b, conv_b, logits);
  k_pol0<<<BATCH, 256, 0, stream>>>(m0, conv_w, logits);

  for (int t=0; t<SEQ; ++t)
    k_step<<<64, 256, 0, stream>>>(xg, w_swz, conv_w, logits, cbuf, memw, hs, h_bf, t);

  // decoded = hs @ enc^T + dec_bias   (4096x32000x1024 bf16 MFMA)
  dim3 gdec(250, 32);
  k_gemm_bf16<<<gdec, 256, 0, stream>>>(hs, nullptr, enc, dbias, nullptr, out, NINP, NVOCAB);

  k_tail<<<1280, 256, 0, stream>>>(hs, cbuf, memw, out);
}

// Round 5
// 3999.137 us; speedup vs baseline: 2.5671x; 1.7900x over previous
//
#include <hip/hip_runtime.h>
#include <math.h>

#define SEQ    128
#define BATCH  32
#define NINP   1024
#define NGATE  4096   // 4*NINP
#define DEPTH  10
#define NPOL   22     // 2*(DEPTH+1)
#define NVOCAB 32000
#define DEC_OFF 131072000ll   // SEQ*BATCH*NVOCAB
#define NBLK   64             // k_step blocks (16-col n-slices)

typedef __attribute__((ext_vector_type(8))) short bf16x8;
typedef __attribute__((ext_vector_type(4))) float f32x4;

__device__ __forceinline__ float sigf(float x){ return 1.0f/(1.0f + expf(-x)); }

__device__ __forceinline__ unsigned short f2bf(float x){
  unsigned int u = __float_as_uint(x);
  unsigned int r = (u + 0x7FFFu + ((u >> 16) & 1u)) >> 16;   // RNE
  return (unsigned short)r;
}

// ---------------- init: c0 (slab layout), memory0 -> [b][n][d], h0 -> bf16 ----------------
__global__ __launch_bounds__(256) void k_init(const float* __restrict__ h0,
    const float* __restrict__ c0, const float* __restrict__ m0,
    float* __restrict__ cbuf, float* __restrict__ memw, unsigned short* __restrict__ h_bf0){
  int i = blockIdx.x*256 + threadIdx.x;
  if (i < BATCH*NINP){
    int b = i >> 10, n = i & 1023;
    cbuf[(n>>4)*512 + b*16 + (n&15)] = c0[i];
    h_bf0[i] = f2bf(h0[i]);
  }
  if (i < BATCH*DEPTH*NINP){
    int b = i/10240, r = i - b*10240, d = r >> 10, n = r & 1023;
    memw[((size_t)b*NINP + n)*DEPTH + d] = m0[i];
  }
}

// ---------------- w_hh -> bf16, swizzled to per-wave MFMA fragment layout ----------------
__global__ __launch_bounds__(256) void k_wconv(const float* __restrict__ w_hh,
    unsigned short* __restrict__ w_swz){
  int id = blockIdx.x*256 + threadIdx.x;          // 0..524287
  int lane = id & 63, kc = (id>>6)&7, kq = (id>>9)&3, nt = id>>11;
  int j = nt*16 + (lane&15);
  int k = kq*256 + kc*32 + (lane>>4)*8;
  const float* src = w_hh + (size_t)j*NINP + k;
  bf16x8 d;
  #pragma unroll
  for (int e=0;e<8;e++) d[e] = (short)f2bf(src[e]);
  *(bf16x8*)(w_swz + (size_t)id*8) = d;
}

// ---------------- bf16 MFMA GEMM (f32 sources): C[m,n] = sum_k A[m,k]*B[n,k] + bias ----------------
__global__ __launch_bounds__(256) void k_gemm_bf16(
    const float* __restrict__ A, const int* __restrict__ Aidx,
    const float* __restrict__ B, const float* __restrict__ bias0,
    const float* __restrict__ bias1, float* __restrict__ C,
    int K, int ldc){
  __shared__ __align__(16) unsigned short As[128][40];
  __shared__ __align__(16) unsigned short Bs[128][40];
  const int m1 = blockIdx.y*128, n1 = blockIdx.x*128;
  const int tid = threadIdx.x;
  const int wave = tid >> 6, lane = tid & 63;
  const int wr = (wave >> 1) * 64, wc = (wave & 1) * 64;
  const int fr = lane & 15, fq = lane >> 4;

  f32x4 acc[4][4];
  #pragma unroll
  for (int i=0;i<4;i++)
    #pragma unroll
    for (int j=0;j<4;j++) acc[i][j] = (f32x4){0.f,0.f,0.f,0.f};

  const int sr = tid >> 1, sk = (tid & 1) * 16;
  const float* arow = Aidx ? (A + (size_t)Aidx[m1+sr]*K) : (A + (size_t)(m1+sr)*K);
  const float* brow = B + (size_t)(n1+sr)*K;

  for (int k0 = 0; k0 < K; k0 += 32){
    float4 a0 = *(const float4*)(arow + k0 + sk);
    float4 a1 = *(const float4*)(arow + k0 + sk + 4);
    float4 a2 = *(const float4*)(arow + k0 + sk + 8);
    float4 a3 = *(const float4*)(arow + k0 + sk + 12);
    float4 b0 = *(const float4*)(brow + k0 + sk);
    float4 b1 = *(const float4*)(brow + k0 + sk + 4);
    float4 b2 = *(const float4*)(brow + k0 + sk + 8);
    float4 b3 = *(const float4*)(brow + k0 + sk + 12);
    bf16x8 ap0, ap1, bp0, bp1;
    ap0[0]=f2bf(a0.x); ap0[1]=f2bf(a0.y); ap0[2]=f2bf(a0.z); ap0[3]=f2bf(a0.w);
    ap0[4]=f2bf(a1.x); ap0[5]=f2bf(a1.y); ap0[6]=f2bf(a1.z); ap0[7]=f2bf(a1.w);
    ap1[0]=f2bf(a2.x); ap1[1]=f2bf(a2.y); ap1[2]=f2bf(a2.z); ap1[3]=f2bf(a2.w);
    ap1[4]=f2bf(a3.x); ap1[5]=f2bf(a3.y); ap1[6]=f2bf(a3.z); ap1[7]=f2bf(a3.w);
    bp0[0]=f2bf(b0.x); bp0[1]=f2bf(b0.y); bp0[2]=f2bf(b0.z); bp0[3]=f2bf(b0.w);
    bp0[4]=f2bf(b1.x); bp0[5]=f2bf(b1.y); bp0[6]=f2bf(b1.z); bp0[7]=f2bf(b1.w);
    bp1[0]=f2bf(b2.x); bp1[1]=f2bf(b2.y); bp1[2]=f2bf(b2.z); bp1[3]=f2bf(b2.w);
    bp1[4]=f2bf(b3.x); bp1[5]=f2bf(b3.y); bp1[6]=f2bf(b3.z); bp1[7]=f2bf(b3.w);

    __syncthreads();
    *(bf16x8*)&As[sr][sk]     = ap0;
    *(bf16x8*)&As[sr][sk + 8] = ap1;
    *(bf16x8*)&Bs[sr][sk]     = bp0;
    *(bf16x8*)&Bs[sr][sk + 8] = bp1;
    __syncthreads();

    bf16x8 af[4], bf[4];
    #pragma unroll
    for (int mi=0; mi<4; mi++) af[mi] = *(const bf16x8*)&As[wr + mi*16 + fr][fq*8];
    #pragma unroll
    for (int ni=0; ni<4; ni++) bf[ni] = *(const bf16x8*)&Bs[wc + ni*16 + fr][fq*8];
    #pragma unroll
    for (int mi=0; mi<4; mi++)
      #pragma unroll
      for (int ni=0; ni<4; ni++)
        acc[mi][ni] = __builtin_amdgcn_mfma_f32_16x16x32_bf16(af[mi], bf[ni], acc[mi][ni], 0, 0, 0);
  }

  #pragma unroll
  for (int ni=0; ni<4; ni++){
    const int col = n1 + wc + ni*16 + fr;
    const float bv = (bias0 ? bias0[col] : 0.f) + (bias1 ? bias1[col] : 0.f);
    #pragma unroll
    for (int mi=0; mi<4; mi++){
      const int row0 = m1 + wr + mi*16 + fq*4;
      #pragma unroll
      for (int j=0; j<4; j++)
        C[(size_t)(row0 + j)*ldc + col] = acc[mi][ni][j] + bv;
    }
  }
}

// ---------------- decode GEMM: A bf16 (4096x1024), B f32 (32000x1024), M-fast grid ----------------
__global__ __launch_bounds__(256) void k_gemm_dec(
    const unsigned short* __restrict__ A, const float* __restrict__ B,
    const float* __restrict__ bias, float* __restrict__ C){
  __shared__ __align__(16) unsigned short As[128][40];
  __shared__ __align__(16) unsigned short Bs[128][40];
  const int m1 = blockIdx.x*128, n1 = blockIdx.y*128;   // x = M (fast) for B-panel L3 reuse
  const int tid = threadIdx.x;
  const int wave = tid >> 6, lane = tid & 63;
  const int wr = (wave >> 1) * 64, wc = (wave & 1) * 64;
  const int fr = lane & 15, fq = lane >> 4;

  f32x4 acc[4][4];
  #pragma unroll
  for (int i=0;i<4;i++)
    #pragma unroll
    for (int j=0;j<4;j++) acc[i][j] = (f32x4){0.f,0.f,0.f,0.f};

  const int sr = tid >> 1, sk = (tid & 1) * 16;
  const unsigned short* arow = A + (size_t)(m1+sr)*NINP;
  const float* brow = B + (size_t)(n1+sr)*NINP;

  for (int k0 = 0; k0 < NINP; k0 += 32){
    bf16x8 ap0 = *(const bf16x8*)(arow + k0 + sk);
    bf16x8 ap1 = *(const bf16x8*)(arow + k0 + sk + 8);
    float4 b0 = *(const float4*)(brow + k0 + sk);
    float4 b1 = *(const float4*)(brow + k0 + sk + 4);
    float4 b2 = *(const float4*)(brow + k0 + sk + 8);
    float4 b3 = *(const float4*)(brow + k0 + sk + 12);
    bf16x8 bp0, bp1;
    bp0[0]=f2bf(b0.x); bp0[1]=f2bf(b0.y); bp0[2]=f2bf(b0.z); bp0[3]=f2bf(b0.w);
    bp0[4]=f2bf(b1.x); bp0[5]=f2bf(b1.y); bp0[6]=f2bf(b1.z); bp0[7]=f2bf(b1.w);
    bp1[0]=f2bf(b2.x); bp1[1]=f2bf(b2.y); bp1[2]=f2bf(b2.z); bp1[3]=f2bf(b2.w);
    bp1[4]=f2bf(b3.x); bp1[5]=f2bf(b3.y); bp1[6]=f2bf(b3.z); bp1[7]=f2bf(b3.w);

    __syncthreads();
    *(bf16x8*)&As[sr][sk]     = ap0;
    *(bf16x8*)&As[sr][sk + 8] = ap1;
    *(bf16x8*)&Bs[sr][sk]     = bp0;
    *(bf16x8*)&Bs[sr][sk + 8] = bp1;
    __syncthreads();

    bf16x8 af[4], bf[4];
    #pragma unroll
    for (int mi=0; mi<4; mi++) af[mi] = *(const bf16x8*)&As[wr + mi*16 + fr][fq*8];
    #pragma unroll
    for (int ni=0; ni<4; ni++) bf[ni] = *(const bf16x8*)&Bs[wc + ni*16 + fr][fq*8];
    #pragma unroll
    for (int mi=0; mi<4; mi++)
      #pragma unroll
      for (int ni=0; ni<4; ni++)
        acc[mi][ni] = __builtin_amdgcn_mfma_f32_16x16x32_bf16(af[mi], bf[ni], acc[mi][ni], 0, 0, 0);
  }

  #pragma unroll
  for (int ni=0; ni<4; ni++){
    const int col = n1 + wc + ni*16 + fr;
    const float bv = bias[col];
    #pragma unroll
    for (int mi=0; mi<4; mi++){
      const int row0 = m1 + wr + mi*16 + fq*4;
      #pragma unroll
      for (int j=0; j<4; j++)
        C[(size_t)(row0 + j)*NVOCAB + col] = acc[mi][ni][j] + bv;
    }
  }
}

// ---------------- logit_base[t][b][p] = emb.pol_w[p] + pol_b[p] + conv_b[p/11] ----------------
__global__ __launch_bounds__(256) void k_xp(const float* __restrict__ enc,
    const int* __restrict__ inputs, const float* __restrict__ pol_w,
    const float* __restrict__ pol_b, const float* __restrict__ conv_b,
    float* __restrict__ logit_base){
  const int m = blockIdx.x;
  const float* x = enc + (size_t)inputs[m]*NINP;
  __shared__ float xs[NINP];
  for (int i=threadIdx.x; i<NINP; i+=256) xs[i] = x[i];
  __syncthreads();
  const int wave = threadIdx.x >> 6, lane = threadIdx.x & 63;
  for (int p = wave; p < NPOL; p += 4){
    const float* w = pol_w + (size_t)p*NINP;
    float s = 0.f;
    for (int k=lane; k<NINP; k+=64) s = fmaf(xs[k], w[k], s);
    #pragma unroll
    for (int off=32; off; off>>=1) s += __shfl_down(s, off);
    if (lane==0) logit_base[(size_t)m*NPOL + p] = s + pol_b[p] + conv_b[p/11];
  }
}

// ---------------- seed logit_base[0] with conv(mem0) ----------------
__global__ __launch_bounds__(256) void k_pol0(const float* __restrict__ m0,
    const float* __restrict__ conv_w, float* __restrict__ logit_base){
  const int b = blockIdx.x;
  const int wave = threadIdx.x >> 6, lane = threadIdx.x & 63;
  for (int p = wave; p < NPOL; p += 4){
    const int o = p/11, tp = p - o*11;
    float s = 0.f;
    if (tp < DEPTH){
      const float* mr = m0 + ((size_t)b*DEPTH + tp)*NINP;
      for (int n=lane; n<NINP; n+=64) s = fmaf(mr[n], conv_w[o*2*NINP + 2*n], s);
    }
    if (tp+1 < DEPTH){
      const float* mr = m0 + ((size_t)b*DEPTH + tp + 1)*NINP;
      for (int n=lane; n<NINP; n+=64) s = fmaf(mr[n], conv_w[o*2*NINP + 2*n + 1], s);
    }
    #pragma unroll
    for (int off=32; off; off>>=1) s += __shfl_down(s, off);
    if (lane==0) logit_base[b*NPOL + p] += s;
  }
}

// ---------------- fused step: 64 blocks, no grid sync, no atomics ----------------
__global__ __launch_bounds__(256) void k_step(
    const float* __restrict__ xg, const unsigned short* __restrict__ w_swz,
    const float* __restrict__ conv_w, const float* __restrict__ logit_base,
    const float* __restrict__ lpR, float* __restrict__ lpW,
    float* __restrict__ cbuf, float* __restrict__ memw,
    unsigned short* __restrict__ hs_bf, float* __restrict__ hlast,
    const unsigned short* __restrict__ hbR, unsigned short* __restrict__ hbW, int t){
  const int blk = blockIdx.x, tid = threadIdx.x;
  const int q = tid >> 6, lane = tid & 63;
  const int fr = lane & 15, fq = lane >> 4;
  const int n0 = blk * 16;

  // w_hh fragments (L2/L3-resident, 128KB/block)
  bf16x8 wreg[32];
  const unsigned short* wb = w_swz + ((size_t)(q*64 + blk)*32*64 + lane)*8;
  #pragma unroll
  for (int ks=0; ks<32; ks++) wreg[ks] = *(const bf16x8*)(wb + ks*512);

  // stage h (32x1024 bf16) into XOR-swizzled LDS
  __shared__ __align__(16) unsigned short hlds[32*1024];
  {
    const int b = tid >> 3, seg = tid & 7;
    const bf16x8* src = (const bf16x8*)(hbR + b*NINP + seg*128);
    #pragma unroll
    for (int i=0;i<16;i++){
      int chunk = seg*16 + i;
      ((bf16x8*)hlds)[b*128 + (chunk ^ (b&7))] = src[i];
    }
  }

  // logits = base + sum over 64 block-partials (from step t-1), then softmax
  __shared__ float spol[32][NPOL];
  for (int idx = tid; idx < BATCH*NPOL; idx += 256){
    float v = logit_base[(size_t)t*BATCH*NPOL + idx];
    if (lpR){
      #pragma unroll 8
      for (int k=0;k<NBLK;k++) v += lpR[k*BATCH*NPOL + idx];
    }
    spol[idx/NPOL][idx - (idx/NPOL)*NPOL] = v;
  }
  __syncthreads();
  if (tid < 32){
    float l[NPOL]; float mx = -1e30f;
    #pragma unroll
    for (int p=0;p<NPOL;p++){ l[p] = spol[tid][p]; mx = fmaxf(mx, l[p]); }
    float sum = 0.f;
    #pragma unroll
    for (int p=0;p<NPOL;p++){ l[p] = expf(l[p]-mx); sum += l[p]; }
    float inv = 1.f/sum;
    #pragma unroll
    for (int p=0;p<NPOL;p++) spol[tid][p] = l[p]*inv;
  }
  __syncthreads();

  // matmul: gates_raw[b, q*1024 + n0 + fr] over K=1024
  f32x4 acc0 = {0.f,0.f,0.f,0.f}, acc1 = {0.f,0.f,0.f,0.f};
  #pragma unroll
  for (int ks=0; ks<32; ks++){
    bf16x8 a0 = ((const bf16x8*)hlds)[fr*128      + ((ks*4 + fq) ^ (fr&7))];
    bf16x8 a1 = ((const bf16x8*)hlds)[(16+fr)*128 + ((ks*4 + fq) ^ (fr&7))];
    acc0 = __builtin_amdgcn_mfma_f32_16x16x32_bf16(a0, wreg[ks], acc0, 0,0,0);
    acc1 = __builtin_amdgcn_mfma_f32_16x16x32_bf16(a1, wreg[ks], acc1, 0,0,0);
  }

  // exchange gates via LDS: gl[b][q*16 + j]
  __shared__ float gl[32][68];
  #pragma unroll
  for (int r=0;r<4;r++){
    gl[fq*4 + r][q*16 + fr]      = acc0[r];
    gl[16 + fq*4 + r][q*16 + fr] = acc1[r];
  }
  __syncthreads();

  // LSTM elementwise + stack memory update + policy partials (plain stores)
  #pragma unroll
  for (int half=0; half<2; half++){
    const int e = tid + half*256;
    const int b = e >> 4, j = e & 15, n = n0 + j;
    const float* xr = xg + ((size_t)t*BATCH + b)*NGATE + n;
    float gi = sigf (gl[b][j]      + xr[0]);
    float gf = sigf (gl[b][16+j]   + xr[NINP]);
    float gg = tanhf(gl[b][32+j]   + xr[2*NINP]);
    float go = sigf (gl[b][48+j]   + xr[3*NINP]);
    float cc = gf*cbuf[blk*512 + e] + gi*gg;
    float hh = go*tanhf(cc);
    cbuf[blk*512 + e] = cc;
    unsigned short hb = f2bf(hh);
    hs_bf[(size_t)t*(BATCH*NINP) + b*NINP + n] = hb;
    hbW[b*NINP + n] = hb;
    hlast[b*NINP + n] = hh;

    float p_[NPOL];
    #pragma unroll
    for (int k2=0;k2<NPOL;k2++) p_[k2] = spol[b][k2];
    float psum = 0.f;
    #pragma unroll
    for (int k2=11;k2<22;k2++) psum += p_[k2];

    float* mw = memw + ((size_t)b*NINP + n)*DEPTH;
    float m[DEPTH];
    #pragma unroll
    for (int d=0;d<DEPTH;d++) m[d] = mw[d];
    float outv[DEPTH];
    {
      float v = psum*hh;
      #pragma unroll
      for (int jj=0;jj<DEPTH;jj++) v = fmaf(p_[jj], m[jj], v);
      outv[0] = v;
    }
    #pragma unroll
    for (int d=1; d<DEPTH; d++){
      float v = 0.f;
      for (int jj=d;   jj<DEPTH; jj++) v = fmaf(p_[jj-d],    m[jj], v);
      for (int jj=d-1; jj<DEPTH; jj++) v = fmaf(p_[12+jj-d], m[jj], v);
      outv[d] = v;
    }
    #pragma unroll
    for (int d=0;d<DEPTH;d++) mw[d] = outv[d];

    // policy partials for step t+1: reduce over the 16 j-lanes, plain store
    const float c00 = conv_w[2*n],          c01 = conv_w[2*n + 1];
    const float c10 = conv_w[2*NINP + 2*n], c11 = conv_w[2*NINP + 2*n + 1];
    #pragma unroll
    for (int o2=0;o2<2;o2++){
      const float ca = o2 ? c10 : c00, cb = o2 ? c11 : c01;
      #pragma unroll
      for (int tp=0; tp<11; tp++){
        float v = 0.f;
        if (tp < DEPTH)   v = outv[tp]*ca;
        if (tp+1 < DEPTH) v = fmaf(outv[tp+1], cb, v);
        v += __shfl_xor(v, 1); v += __shfl_xor(v, 2);
        v += __shfl_xor(v, 4); v += __shfl_xor(v, 8);
        if (j == 0) lpW[(size_t)blk*(BATCH*NPOL) + b*NPOL + o2*11 + tp] = v;
      }
    }
  }
}

// ---------------- tail: hT, cT, memT (undo working layouts) ----------------
__global__ __launch_bounds__(256) void k_tail(const float* __restrict__ hlast,
    const float* __restrict__ cbuf, const float* __restrict__ memw,
    float* __restrict__ out){
  int i = blockIdx.x*256 + threadIdx.x;
  float* o = out + DEC_OFF;
  if (i < BATCH*NINP){
    int b = i >> 10, n = i & 1023;
    o[i] = hlast[i];
    o[BATCH*NINP + i] = cbuf[(n>>4)*512 + b*16 + (n&15)];
  }
  if (i < BATCH*DEPTH*NINP){
    int b = i/10240, r = i - b*10240, d = r >> 10, n = r & 1023;
    o[2*BATCH*NINP + i] = memw[((size_t)b*NINP + n)*DEPTH + d];
  }
}

extern "C" void kernel_launch(void* const* d_in, const int* in_sizes, int n_in,
                              void* d_out, int out_size, void* d_ws, size_t ws_size,
                              hipStream_t stream){
  (void)in_sizes; (void)n_in; (void)out_size; (void)ws_size;
  const int*   inputs = (const int*)  d_in[0];
  const float* h0     = (const float*)d_in[1];
  const float* c0     = (const float*)d_in[2];
  const float* m0     = (const float*)d_in[3];
  const float* enc    = (const float*)d_in[4];
  const float* dbias  = (const float*)d_in[5];
  const float* w_ih   = (const float*)d_in[6];
  const float* w_hh   = (const float*)d_in[7];
  const float* b_ih   = (const float*)d_in[8];
  const float* b_hh   = (const float*)d_in[9];
  const float* conv_w = (const float*)d_in[10];
  const float* conv_b = (const float*)d_in[11];
  const float* pol_w  = (const float*)d_in[12];
  const float* pol_b  = (const float*)d_in[13];

  float* out = (float*)d_out;
  float* ws  = (float*)d_ws;
  // ws layout (float slots): cbuf 32768 | memw 327680 | logit_base 90112 | lpart 2*45056 |
  //                          hlast 32768 | hs_bf 2097152 (as ushort[4194304])
  float* cbuf   = ws;
  float* memw   = cbuf  + 32768;
  float* lbase  = memw  + 327680;
  float* lpart  = lbase + 90112;
  float* hlast  = lpart + 90112;
  unsigned short* hs_bf = (unsigned short*)(hlast + 32768);
  // scratch inside decoded region of d_out (dead before decode writes):
  float* xg = out;                                              // 16,777,216 floats
  unsigned short* w_swz = (unsigned short*)(out + 17000000);    // 4.2M shorts
  unsigned short* h_bf0 = (unsigned short*)(out + 19500000);    // 32768 shorts
  unsigned short* h_bf1 = (unsigned short*)(out + 19600000);    // 32768 shorts

  k_init<<<1280, 256, 0, stream>>>(h0, c0, m0, cbuf, memw, h_bf0);
  k_wconv<<<2048, 256, 0, stream>>>(w_hh, w_swz);

  // xg[m,j] = emb(m).w_ih[j] + b_ih[j] + b_hh[j]   (4096x4096x1024 bf16 MFMA)
  dim3 gxg(32, 32);
  k_gemm_bf16<<<gxg, 256, 0, stream>>>(enc, inputs, w_ih, b_ih, b_hh, xg, NINP, NGATE);

  k_xp<<<SEQ*BATCH, 256, 0, stream>>>(enc, inputs, pol_w, pol_b, conv_b, lbase);
  k_pol0<<<BATCH, 256, 0, stream>>>(m0, conv_w, lbase);

  for (int t=0; t<SEQ; ++t){
    const float* lpR = (t == 0) ? nullptr : lpart + ((t+1)&1)*(NBLK*BATCH*NPOL);
    float* lpW = lpart + (t&1)*(NBLK*BATCH*NPOL);
    const unsigned short* hbR = (t&1) ? h_bf1 : h_bf0;
    unsigned short* hbW = (t&1) ? h_bf0 : h_bf1;
    k_step<<<NBLK, 256, 0, stream>>>(xg, w_swz, conv_w, lbase, lpR, lpW,
                                     cbuf, memw, hs_bf, hlast, hbR, hbW, t);
  }

  // decoded = hs_bf @ enc^T + dec_bias   (4096x32000x1024, A bf16, M-fast grid)
  dim3 gdec(32, 250);
  k_gemm_dec<<<gdec, 256, 0, stream>>>(hs_bf, enc, dbias, out);

  k_tail<<<1280, 256, 0, stream>>>(hlast, cbuf, memw, out);
}

// Round 7
// 3786.851 us; speedup vs baseline: 2.7110x; 1.0561x over previous
//
#include <hip/hip_runtime.h>
#include <math.h>

#define SEQ    128
#define BATCH  32
#define NINP   1024
#define NGATE  4096   // 4*NINP
#define DEPTH  10
#define NPOL   22     // 2*(DEPTH+1)
#define NVOCAB 32000
#define DEC_OFF 131072000ll   // SEQ*BATCH*NVOCAB
#define NBLK   64             // k_step blocks (16-col n-slices)

typedef __attribute__((ext_vector_type(8))) short bf16x8;
typedef __attribute__((ext_vector_type(4))) float f32x4;

__device__ __forceinline__ float sigf(float x){ return 1.0f/(1.0f + expf(-x)); }

__device__ __forceinline__ unsigned short f2bf(float x){
  unsigned int u = __float_as_uint(x);
  unsigned int r = (u + 0x7FFFu + ((u >> 16) & 1u)) >> 16;   // RNE
  return (unsigned short)r;
}

// ---------------- init: c0 (slab layout), memory0 -> [b][n][d], h0 -> bf16 ----------------
__global__ __launch_bounds__(256) void k_init(const float* __restrict__ h0,
    const float* __restrict__ c0, const float* __restrict__ m0,
    float* __restrict__ cbuf, float* __restrict__ memw, unsigned short* __restrict__ h_bf0){
  int i = blockIdx.x*256 + threadIdx.x;
  if (i < BATCH*NINP){
    int b = i >> 10, n = i & 1023;
    cbuf[(n>>4)*512 + b*16 + (n&15)] = c0[i];
    h_bf0[i] = f2bf(h0[i]);
  }
  if (i < BATCH*DEPTH*NINP){
    int b = i/10240, r = i - b*10240, d = r >> 10, n = r & 1023;
    memw[((size_t)b*NINP + n)*DEPTH + d] = m0[i];
  }
}

// ---------------- w_hh -> bf16, swizzled to per-wave MFMA fragment layout ----------------
__global__ __launch_bounds__(256) void k_wconv(const float* __restrict__ w_hh,
    unsigned short* __restrict__ w_swz){
  int id = blockIdx.x*256 + threadIdx.x;          // 0..524287
  int lane = id & 63, kc = (id>>6)&7, kq = (id>>9)&3, nt = id>>11;
  int j = nt*16 + (lane&15);
  int k = kq*256 + kc*32 + (lane>>4)*8;
  const float* src = w_hh + (size_t)j*NINP + k;
  bf16x8 d;
  #pragma unroll
  for (int e=0;e<8;e++) d[e] = (short)f2bf(src[e]);
  *(bf16x8*)(w_swz + (size_t)id*8) = d;
}

// ---------------- enc f32 -> bf16 (row-major copy) ----------------
__global__ __launch_bounds__(256) void k_enc(const float* __restrict__ enc,
    unsigned short* __restrict__ enc_bf){
  size_t gid = (size_t)blockIdx.x*256 + threadIdx.x;   // < 2,048,000
  const float* s = enc + gid*16;
  float4 a0 = *(const float4*)(s);
  float4 a1 = *(const float4*)(s+4);
  float4 a2 = *(const float4*)(s+8);
  float4 a3 = *(const float4*)(s+12);
  bf16x8 o0, o1;
  o0[0]=f2bf(a0.x); o0[1]=f2bf(a0.y); o0[2]=f2bf(a0.z); o0[3]=f2bf(a0.w);
  o0[4]=f2bf(a1.x); o0[5]=f2bf(a1.y); o0[6]=f2bf(a1.z); o0[7]=f2bf(a1.w);
  o1[0]=f2bf(a2.x); o1[1]=f2bf(a2.y); o1[2]=f2bf(a2.z); o1[3]=f2bf(a2.w);
  o1[4]=f2bf(a3.x); o1[5]=f2bf(a3.y); o1[6]=f2bf(a3.z); o1[7]=f2bf(a3.w);
  *(bf16x8*)(enc_bf + gid*16)     = o0;
  *(bf16x8*)(enc_bf + gid*16 + 8) = o1;
}

// ---------------- bf16 MFMA GEMM (f32 sources, reg-staged): C = A.B^T + bias ----------------
__global__ __launch_bounds__(256) void k_gemm_bf16(
    const float* __restrict__ A, const int* __restrict__ Aidx,
    const float* __restrict__ B, const float* __restrict__ bias0,
    const float* __restrict__ bias1, float* __restrict__ C,
    int K, int ldc){
  __shared__ __align__(16) unsigned short As[128][40];
  __shared__ __align__(16) unsigned short Bs[128][40];
  const int m1 = blockIdx.y*128, n1 = blockIdx.x*128;
  const int tid = threadIdx.x;
  const int wave = tid >> 6, lane = tid & 63;
  const int wr = (wave >> 1) * 64, wc = (wave & 1) * 64;
  const int fr = lane & 15, fq = lane >> 4;

  f32x4 acc[4][4];
  #pragma unroll
  for (int i=0;i<4;i++)
    #pragma unroll
    for (int j=0;j<4;j++) acc[i][j] = (f32x4){0.f,0.f,0.f,0.f};

  const int sr = tid >> 1, sk = (tid & 1) * 16;
  const float* arow = Aidx ? (A + (size_t)Aidx[m1+sr]*K) : (A + (size_t)(m1+sr)*K);
  const float* brow = B + (size_t)(n1+sr)*K;

  for (int k0 = 0; k0 < K; k0 += 32){
    float4 a0 = *(const float4*)(arow + k0 + sk);
    float4 a1 = *(const float4*)(arow + k0 + sk + 4);
    float4 a2 = *(const float4*)(arow + k0 + sk + 8);
    float4 a3 = *(const float4*)(arow + k0 + sk + 12);
    float4 b0 = *(const float4*)(brow + k0 + sk);
    float4 b1 = *(const float4*)(brow + k0 + sk + 4);
    float4 b2 = *(const float4*)(brow + k0 + sk + 8);
    float4 b3 = *(const float4*)(brow + k0 + sk + 12);
    bf16x8 ap0, ap1, bp0, bp1;
    ap0[0]=f2bf(a0.x); ap0[1]=f2bf(a0.y); ap0[2]=f2bf(a0.z); ap0[3]=f2bf(a0.w);
    ap0[4]=f2bf(a1.x); ap0[5]=f2bf(a1.y); ap0[6]=f2bf(a1.z); ap0[7]=f2bf(a1.w);
    ap1[0]=f2bf(a2.x); ap1[1]=f2bf(a2.y); ap1[2]=f2bf(a2.z); ap1[3]=f2bf(a2.w);
    ap1[4]=f2bf(a3.x); ap1[5]=f2bf(a3.y); ap1[6]=f2bf(a3.z); ap1[7]=f2bf(a3.w);
    bp0[0]=f2bf(b0.x); bp0[1]=f2bf(b0.y); bp0[2]=f2bf(b0.z); bp0[3]=f2bf(b0.w);
    bp0[4]=f2bf(b1.x); bp0[5]=f2bf(b1.y); bp0[6]=f2bf(b1.z); bp0[7]=f2bf(b1.w);
    bp1[0]=f2bf(b2.x); bp1[1]=f2bf(b2.y); bp1[2]=f2bf(b2.z); bp1[3]=f2bf(b2.w);
    bp1[4]=f2bf(b3.x); bp1[5]=f2bf(b3.y); bp1[6]=f2bf(b3.z); bp1[7]=f2bf(b3.w);

    __syncthreads();
    *(bf16x8*)&As[sr][sk]     = ap0;
    *(bf16x8*)&As[sr][sk + 8] = ap1;
    *(bf16x8*)&Bs[sr][sk]     = bp0;
    *(bf16x8*)&Bs[sr][sk + 8] = bp1;
    __syncthreads();

    bf16x8 af[4], bf[4];
    #pragma unroll
    for (int mi=0; mi<4; mi++) af[mi] = *(const bf16x8*)&As[wr + mi*16 + fr][fq*8];
    #pragma unroll
    for (int ni=0; ni<4; ni++) bf[ni] = *(const bf16x8*)&Bs[wc + ni*16 + fr][fq*8];
    #pragma unroll
    for (int mi=0; mi<4; mi++)
      #pragma unroll
      for (int ni=0; ni<4; ni++)
        acc[mi][ni] = __builtin_amdgcn_mfma_f32_16x16x32_bf16(af[mi], bf[ni], acc[mi][ni], 0, 0, 0);
  }

  #pragma unroll
  for (int ni=0; ni<4; ni++){
    const int col = n1 + wc + ni*16 + fr;
    const float bv = (bias0 ? bias0[col] : 0.f) + (bias1 ? bias1[col] : 0.f);
    #pragma unroll
    for (int mi=0; mi<4; mi++){
      const int row0 = m1 + wr + mi*16 + fq*4;
      #pragma unroll
      for (int j=0; j<4; j++)
        C[(size_t)(row0 + j)*ldc + col] = acc[mi][ni][j] + bv;
    }
  }
}

// ---------------- decode fallback (A bf16, B f32): used when ws too small ----------------
__global__ __launch_bounds__(256) void k_gemm_dec(
    const unsigned short* __restrict__ A, const float* __restrict__ B,
    const float* __restrict__ bias, float* __restrict__ C){
  __shared__ __align__(16) unsigned short As[128][40];
  __shared__ __align__(16) unsigned short Bs[128][40];
  const int m1 = blockIdx.x*128, n1 = blockIdx.y*128;
  const int tid = threadIdx.x;
  const int wave = tid >> 6, lane = tid & 63;
  const int wr = (wave >> 1) * 64, wc = (wave & 1) * 64;
  const int fr = lane & 15, fq = lane >> 4;

  f32x4 acc[4][4];
  #pragma unroll
  for (int i=0;i<4;i++)
    #pragma unroll
    for (int j=0;j<4;j++) acc[i][j] = (f32x4){0.f,0.f,0.f,0.f};

  const int sr = tid >> 1, sk = (tid & 1) * 16;
  const unsigned short* arow = A + (size_t)(m1+sr)*NINP;
  const float* brow = B + (size_t)(n1+sr)*NINP;

  for (int k0 = 0; k0 < NINP; k0 += 32){
    bf16x8 ap0 = *(const bf16x8*)(arow + k0 + sk);
    bf16x8 ap1 = *(const bf16x8*)(arow + k0 + sk + 8);
    float4 b0 = *(const float4*)(brow + k0 + sk);
    float4 b1 = *(const float4*)(brow + k0 + sk + 4);
    float4 b2 = *(const float4*)(brow + k0 + sk + 8);
    float4 b3 = *(const float4*)(brow + k0 + sk + 12);
    bf16x8 bp0, bp1;
    bp0[0]=f2bf(b0.x); bp0[1]=f2bf(b0.y); bp0[2]=f2bf(b0.z); bp0[3]=f2bf(b0.w);
    bp0[4]=f2bf(b1.x); bp0[5]=f2bf(b1.y); bp0[6]=f2bf(b1.z); bp0[7]=f2bf(b1.w);
    bp1[0]=f2bf(b2.x); bp1[1]=f2bf(b2.y); bp1[2]=f2bf(b2.z); bp1[3]=f2bf(b2.w);
    bp1[4]=f2bf(b3.x); bp1[5]=f2bf(b3.y); bp1[6]=f2bf(b3.z); bp1[7]=f2bf(b3.w);

    __syncthreads();
    *(bf16x8*)&As[sr][sk]     = ap0;
    *(bf16x8*)&As[sr][sk + 8] = ap1;
    *(bf16x8*)&Bs[sr][sk]     = bp0;
    *(bf16x8*)&Bs[sr][sk + 8] = bp1;
    __syncthreads();

    bf16x8 af[4], bf[4];
    #pragma unroll
    for (int mi=0; mi<4; mi++) af[mi] = *(const bf16x8*)&As[wr + mi*16 + fr][fq*8];
    #pragma unroll
    for (int ni=0; ni<4; ni++) bf[ni] = *(const bf16x8*)&Bs[wc + ni*16 + fr][fq*8];
    #pragma unroll
    for (int mi=0; mi<4; mi++)
      #pragma unroll
      for (int ni=0; ni<4; ni++)
        acc[mi][ni] = __builtin_amdgcn_mfma_f32_16x16x32_bf16(af[mi], bf[ni], acc[mi][ni], 0, 0, 0);
  }

  #pragma unroll
  for (int ni=0; ni<4; ni++){
    const int col = n1 + wc + ni*16 + fr;
    const float bv = bias[col];
    #pragma unroll
    for (int mi=0; mi<4; mi++){
      const int row0 = m1 + wr + mi*16 + fq*4;
      #pragma unroll
      for (int j=0; j<4; j++)
        C[(size_t)(row0 + j)*NVOCAB + col] = acc[mi][ni][j] + bv;
    }
  }
}

// ---------------- decode main (A bf16, B bf16, global_load_lds staging) ----------------
__global__ __launch_bounds__(256) void k_gemm_dec2(
    const unsigned short* __restrict__ A, const unsigned short* __restrict__ B,
    const float* __restrict__ bias, float* __restrict__ C){
  __shared__ __align__(16) unsigned short As[128][32];   // linear (global_load_lds dest)
  __shared__ __align__(16) unsigned short Bs[128][32];
  const int m1 = blockIdx.x*128, n1 = blockIdx.y*128;    // x = M fast: B-panel L2/L3 reuse
  const int tid = threadIdx.x;
  const int wave = tid >> 6, lane = tid & 63;
  const int wr = (wave >> 1) * 64, wc = (wave & 1) * 64;
  const int fr = lane & 15, fq = lane >> 4;

  f32x4 acc[4][4];
  #pragma unroll
  for (int i=0;i<4;i++)
    #pragma unroll
    for (int j=0;j<4;j++) acc[i][j] = (f32x4){0.f,0.f,0.f,0.f};

  // staging: wave w, lane l -> tile row w*16 + (l>>2), 16B seg (l&3)
  const int srow = wave*16 + (lane>>2), scol = (lane&3)*8;
  const unsigned short* ga0 = A + (size_t)(m1 + srow)*NINP + scol;
  const unsigned short* ga1 = ga0 + (size_t)64*NINP;
  const unsigned short* gb0 = B + (size_t)(n1 + srow)*NINP + scol;
  const unsigned short* gb1 = gb0 + (size_t)64*NINP;
  unsigned short* la0 = &As[wave*16][0];
  unsigned short* la1 = &As[64 + wave*16][0];
  unsigned short* lb0 = &Bs[wave*16][0];
  unsigned short* lb1 = &Bs[64 + wave*16][0];

  for (int k0 = 0; k0 < NINP; k0 += 32){
    __syncthreads();   // prior iteration's fragment reads complete
    __builtin_amdgcn_global_load_lds((const unsigned int*)(ga0 + k0), (unsigned int*)la0, 16, 0, 0);
    __builtin_amdgcn_global_load_lds((const unsigned int*)(ga1 + k0), (unsigned int*)la1, 16, 0, 0);
    __builtin_amdgcn_global_load_lds((const unsigned int*)(gb0 + k0), (unsigned int*)lb0, 16, 0, 0);
    __builtin_amdgcn_global_load_lds((const unsigned int*)(gb1 + k0), (unsigned int*)lb1, 16, 0, 0);
    __syncthreads();   // drains vmcnt: staged tile visible

    bf16x8 af[4], bf[4];
    #pragma unroll
    for (int mi=0; mi<4; mi++) af[mi] = *(const bf16x8*)&As[wr + mi*16 + fr][fq*8];
    #pragma unroll
    for (int ni=0; ni<4; ni++) bf[ni] = *(const bf16x8*)&Bs[wc + ni*16 + fr][fq*8];
    #pragma unroll
    for (int mi=0; mi<4; mi++)
      #pragma unroll
      for (int ni=0; ni<4; ni++)
        acc[mi][ni] = __builtin_amdgcn_mfma_f32_16x16x32_bf16(af[mi], bf[ni], acc[mi][ni], 0, 0, 0);
  }

  #pragma unroll
  for (int ni=0; ni<4; ni++){
    const int col = n1 + wc + ni*16 + fr;
    const float bv = bias[col];
    #pragma unroll
    for (int mi=0; mi<4; mi++){
      const int row0 = m1 + wr + mi*16 + fq*4;
      #pragma unroll
      for (int j=0; j<4; j++)
        C[(size_t)(row0 + j)*NVOCAB + col] = acc[mi][ni][j] + bv;
    }
  }
}

// ---------------- logit_base[t][b][p] = emb.pol_w[p] + pol_b[p] + conv_b[p/11] ----------------
__global__ __launch_bounds__(256) void k_xp(const float* __restrict__ enc,
    const int* __restrict__ inputs, const float* __restrict__ pol_w,
    const float* __restrict__ pol_b, const float* __restrict__ conv_b,
    float* __restrict__ logit_base){
  const int m = blockIdx.x;
  const float* x = enc + (size_t)inputs[m]*NINP;
  __shared__ float xs[NINP];
  for (int i=threadIdx.x; i<NINP; i+=256) xs[i] = x[i];
  __syncthreads();
  const int wave = threadIdx.x >> 6, lane = threadIdx.x & 63;
  for (int p = wave; p < NPOL; p += 4){
    const float* w = pol_w + (size_t)p*NINP;
    float s = 0.f;
    for (int k=lane; k<NINP; k+=64) s = fmaf(xs[k], w[k], s);
    #pragma unroll
    for (int off=32; off; off>>=1) s += __shfl_down(s, off);
    if (lane==0) logit_base[(size_t)m*NPOL + p] = s + pol_b[p] + conv_b[p/11];
  }
}

// ---------------- seed logit_base[0] with conv(mem0) ----------------
__global__ __launch_bounds__(256) void k_pol0(const float* __restrict__ m0,
    const float* __restrict__ conv_w, float* __restrict__ logit_base){
  const int b = blockIdx.x;
  const int wave = threadIdx.x >> 6, lane = threadIdx.x & 63;
  for (int p = wave; p < NPOL; p += 4){
    const int o = p/11, tp = p - o*11;
    float s = 0.f;
    if (tp < DEPTH){
      const float* mr = m0 + ((size_t)b*DEPTH + tp)*NINP;
      for (int n=lane; n<NINP; n+=64) s = fmaf(mr[n], conv_w[o*2*NINP + 2*n], s);
    }
    if (tp+1 < DEPTH){
      const float* mr = m0 + ((size_t)b*DEPTH + tp + 1)*NINP;
      for (int n=lane; n<NINP; n+=64) s = fmaf(mr[n], conv_w[o*2*NINP + 2*n + 1], s);
    }
    #pragma unroll
    for (int off=32; off; off>>=1) s += __shfl_down(s, off);
    if (lane==0) logit_base[b*NPOL + p] += s;
  }
}

// ---------------- fused step: 64 blocks x 512 threads ----------------
// waves 0-3: gates matmul (wave = gate quadrant). waves 4-7: logit reduce.
// lpart layout: [idx = b*22+p][64 blk] (coalesced reduction).
__global__ __launch_bounds__(512) void k_step(
    const float* __restrict__ xg, const unsigned short* __restrict__ w_swz,
    const float* __restrict__ conv_w, const float* __restrict__ logit_base,
    const float* __restrict__ lpR, float* __restrict__ lpW,
    float* __restrict__ cbuf, float* __restrict__ memw,
    unsigned short* __restrict__ hs_bf, float* __restrict__ hlast,
    const unsigned short* __restrict__ hbR, unsigned short* __restrict__ hbW, int t){
  const int blk = blockIdx.x, tid = threadIdx.x;
  const int wv = tid >> 6, lane = tid & 63;
  const int fr = lane & 15, fq = lane >> 4;
  const int n0 = blk * 16;

  __shared__ __align__(16) unsigned short hlds[32*1024];
  __shared__ float gl[32][68];
  __shared__ float lsum[BATCH*NPOL];
  __shared__ float spol[32][NPOL];

  // ---- phase 1: prefetch per-thread elementwise operands (HBM latency hides under matmul)
  const int eb = tid >> 4, ej = tid & 15, en = n0 + ej;     // elementwise item = tid
  const float* xr = xg + ((size_t)t*BATCH + eb)*NGATE + en;
  const float xi = xr[0], xf = xr[NINP], xgg = xr[2*NINP], xo = xr[3*NINP];
  const float cold = cbuf[blk*512 + tid];
  float* mw = memw + ((size_t)eb*NINP + en)*DEPTH;
  float m[DEPTH];
  #pragma unroll
  for (int d=0;d<DEPTH;d++) m[d] = mw[d];

  // stage h: 512 threads x 8 chunks of 16B each = 4096 chunks = 32 rows x 128
  {
    const int b = tid >> 4, seg = tid & 15;
    const bf16x8* src = (const bf16x8*)(hbR + b*NINP);
    #pragma unroll
    for (int i=0;i<8;i++){
      int ch = seg*8 + i;                       // 0..127 16B-chunks within the row
      ((bf16x8*)hlds)[b*128 + (ch ^ (b&7))] = src[ch];
    }
  }

  bf16x8 wreg[32];
  if (wv < 4){
    const unsigned short* wb = w_swz + ((size_t)(wv*64 + blk)*32*64 + (size_t)lane)*8;
    #pragma unroll
    for (int ks=0; ks<32; ks++) wreg[ks] = *(const bf16x8*)(wb + (size_t)ks*512);
  } else {
    // logit reduction: 704 idx; 4 waves x 8 idx/wave-iter x 22 iters; 8 lanes per idx
    const int wp = wv - 4;
    const int li = lane >> 3, c8 = lane & 7;
    for (int it=0; it<22; ++it){
      const int idx = (wp + it*4)*8 + li;                   // 0..703
      float v = 0.f;
      if (lpR){
        const float* s = lpR + (size_t)idx*NBLK + c8*8;
        float4 u0 = *(const float4*)s;
        float4 u1 = *(const float4*)(s+4);
        v = (u0.x+u0.y)+(u0.z+u0.w)+((u1.x+u1.y)+(u1.z+u1.w));
      }
      v += __shfl_xor(v,1); v += __shfl_xor(v,2); v += __shfl_xor(v,4);
      if (c8==0) lsum[idx] = v + logit_base[(size_t)t*(BATCH*NPOL) + idx];
    }
  }
  __syncthreads();

  // ---- phase 2: waves 0-3 MFMA; wave-4 lanes do the 32 softmaxes
  if (wv < 4){
    f32x4 acc0 = {0.f,0.f,0.f,0.f}, acc1 = {0.f,0.f,0.f,0.f};
    #pragma unroll
    for (int ks=0; ks<32; ks++){
      bf16x8 a0 = ((const bf16x8*)hlds)[fr*128      + ((ks*4 + fq) ^ (fr&7))];
      bf16x8 a1 = ((const bf16x8*)hlds)[(16+fr)*128 + ((ks*4 + fq) ^ (fr&7))];
      acc0 = __builtin_amdgcn_mfma_f32_16x16x32_bf16(a0, wreg[ks], acc0, 0,0,0);
      acc1 = __builtin_amdgcn_mfma_f32_16x16x32_bf16(a1, wreg[ks], acc1, 0,0,0);
    }
    #pragma unroll
    for (int r=0;r<4;r++){
      gl[fq*4 + r][wv*16 + fr]      = acc0[r];
      gl[16 + fq*4 + r][wv*16 + fr] = acc1[r];
    }
  } else if (tid < 288){
    const int b = tid - 256;
    float l[NPOL]; float mx = -1e30f;
    #pragma unroll
    for (int p=0;p<NPOL;p++){ l[p] = lsum[b*NPOL + p]; mx = fmaxf(mx, l[p]); }
    float sum = 0.f;
    #pragma unroll
    for (int p=0;p<NPOL;p++){ l[p] = expf(l[p]-mx); sum += l[p]; }
    float inv = 1.f/sum;
    #pragma unroll
    for (int p=0;p<NPOL;p++) spol[b][p] = l[p]*inv;
  }
  __syncthreads();

  // ---- phase 3: LSTM elementwise + stack update + policy partials (1 item/thread)
  {
    const int b = eb, n = en;
    float gi = sigf (gl[b][ej]    + xi);
    float gf = sigf (gl[b][16+ej] + xf);
    float gg = tanhf(gl[b][32+ej] + xgg);
    float go = sigf (gl[b][48+ej] + xo);
    float cc = gf*cold + gi*gg;
    float hh = go*tanhf(cc);
    cbuf[blk*512 + tid] = cc;
    unsigned short hb = f2bf(hh);
    hs_bf[(size_t)t*(BATCH*NINP) + b*NINP + n] = hb;
    hbW[b*NINP + n] = hb;
    hlast[b*NINP + n] = hh;

    float p_[NPOL];
    #pragma unroll
    for (int k2=0;k2<NPOL;k2++) p_[k2] = spol[b][k2];
    float psum = 0.f;
    #pragma unroll
    for (int k2=11;k2<22;k2++) psum += p_[k2];

    float outv[DEPTH];
    {
      float v = psum*hh;
      #pragma unroll
      for (int jj=0;jj<DEPTH;jj++) v = fmaf(p_[jj], m[jj], v);
      outv[0] = v;
    }
    #pragma unroll
    for (int d=1; d<DEPTH; d++){
      float v = 0.f;
      for (int jj=d;   jj<DEPTH; jj++) v = fmaf(p_[jj-d],    m[jj], v);
      for (int jj=d-1; jj<DEPTH; jj++) v = fmaf(p_[12+jj-d], m[jj], v);
      outv[d] = v;
    }
    #pragma unroll
    for (int d=0;d<DEPTH;d++) mw[d] = outv[d];

    const float c00 = conv_w[2*n],          c01 = conv_w[2*n + 1];
    const float c10 = conv_w[2*NINP + 2*n], c11 = conv_w[2*NINP + 2*n + 1];
    #pragma unroll
    for (int o2=0;o2<2;o2++){
      const float ca = o2 ? c10 : c00, cb2 = o2 ? c11 : c01;
      #pragma unroll
      for (int tp=0; tp<11; tp++){
        float v = 0.f;
        if (tp < DEPTH)   v = outv[tp]*ca;
        if (tp+1 < DEPTH) v = fmaf(outv[tp+1], cb2, v);
        v += __shfl_xor(v, 1); v += __shfl_xor(v, 2);
        v += __shfl_xor(v, 4); v += __shfl_xor(v, 8);
        if (ej == 0) lpW[(size_t)(b*NPOL + o2*11 + tp)*NBLK + blk] = v;
      }
    }
  }
}

// ---------------- tail: hT, cT, memT (undo working layouts) ----------------
__global__ __launch_bounds__(256) void k_tail(const float* __restrict__ hlast,
    const float* __restrict__ cbuf, const float* __restrict__ memw,
    float* __restrict__ out){
  int i = blockIdx.x*256 + threadIdx.x;
  float* o = out + DEC_OFF;
  if (i < BATCH*NINP){
    int b = i >> 10, n = i & 1023;
    o[i] = hlast[i];
    o[BATCH*NINP + i] = cbuf[(n>>4)*512 + b*16 + (n&15)];
  }
  if (i < BATCH*DEPTH*NINP){
    int b = i/10240, r = i - b*10240, d = r >> 10, n = r & 1023;
    o[2*BATCH*NINP + i] = memw[((size_t)b*NINP + n)*DEPTH + d];
  }
}

extern "C" void kernel_launch(void* const* d_in, const int* in_sizes, int n_in,
                              void* d_out, int out_size, void* d_ws, size_t ws_size,
                              hipStream_t stream){
  (void)in_sizes; (void)n_in; (void)out_size;
  const int*   inputs = (const int*)  d_in[0];
  const float* h0     = (const float*)d_in[1];
  const float* c0     = (const float*)d_in[2];
  const float* m0     = (const float*)d_in[3];
  const float* enc    = (const float*)d_in[4];
  const float* dbias  = (const float*)d_in[5];
  const float* w_ih   = (const float*)d_in[6];
  const float* w_hh   = (const float*)d_in[7];
  const float* b_ih   = (const float*)d_in[8];
  const float* b_hh   = (const float*)d_in[9];
  const float* conv_w = (const float*)d_in[10];
  const float* conv_b = (const float*)d_in[11];
  const float* pol_w  = (const float*)d_in[12];
  const float* pol_b  = (const float*)d_in[13];

  float* out = (float*)d_out;
  float* ws  = (float*)d_ws;
  // ws layout (float slots):
  float* cbuf   = ws;                    // 32768
  float* memw   = cbuf  + 32768;         // 327680
  float* lbase  = memw  + 327680;        // 90112
  float* lpart  = lbase + 90112;         // 2*45056
  float* hlast  = lpart + 90112;         // 32768
  unsigned short* hs_bf  = (unsigned short*)(hlast + 32768);        // 4,194,304 shorts
  unsigned short* enc_bf = (unsigned short*)(hlast + 32768 + 2097152); // 32,768,000 shorts
  const int use_encbf = (ws_size >= (size_t)19060000*4);
  // scratch inside decoded region of d_out (dead before decode writes):
  float* xg = out;                                              // 16,777,216 floats
  unsigned short* w_swz = (unsigned short*)(out + 17000000);    // 4.2M shorts
  unsigned short* h_bf0 = (unsigned short*)(out + 19500000);    // 32768 shorts
  unsigned short* h_bf1 = (unsigned short*)(out + 19600000);    // 32768 shorts

  k_init<<<1280, 256, 0, stream>>>(h0, c0, m0, cbuf, memw, h_bf0);
  k_wconv<<<2048, 256, 0, stream>>>(w_hh, w_swz);
  if (use_encbf) k_enc<<<8000, 256, 0, stream>>>(enc, enc_bf);

  // xg[m,j] = emb(m).w_ih[j] + b_ih[j] + b_hh[j]   (4096x4096x1024 bf16 MFMA)
  dim3 gxg(32, 32);
  k_gemm_bf16<<<gxg, 256, 0, stream>>>(enc, inputs, w_ih, b_ih, b_hh, xg, NINP, NGATE);

  k_xp<<<SEQ*BATCH, 256, 0, stream>>>(enc, inputs, pol_w, pol_b, conv_b, lbase);
  k_pol0<<<BATCH, 256, 0, stream>>>(m0, conv_w, lbase);

  for (int t=0; t<SEQ; ++t){
    const float* lpR = (t == 0) ? nullptr : lpart + ((t+1)&1)*(BATCH*NPOL*NBLK);
    float* lpW = lpart + (t&1)*(BATCH*NPOL*NBLK);
    const unsigned short* hbR = (t&1) ? h_bf1 : h_bf0;
    unsigned short* hbW = (t&1) ? h_bf0 : h_bf1;
    k_step<<<NBLK, 512, 0, stream>>>(xg, w_swz, conv_w, lbase, lpR, lpW,
                                     cbuf, memw, hs_bf, hlast, hbR, hbW, t);
  }

  // decoded = hs @ enc^T + dec_bias   (4096x32000x1024)
  dim3 gdec(32, 250);
  if (use_encbf)
    k_gemm_dec2<<<gdec, 256, 0, stream>>>(hs_bf, enc_bf, dbias, out);
  else
    k_gemm_dec<<<gdec, 256, 0, stream>>>(hs_bf, enc, dbias, out);

  k_tail<<<1280, 256, 0, stream>>>(hlast, cbuf, memw, out);
}